// Round 11
// baseline (691.871 us; speedup 1.0000x reference)
//
#include <hip/hip_runtime.h>

typedef __bf16 bf16x8 __attribute__((ext_vector_type(8)));
typedef __bf16 bf16x4 __attribute__((ext_vector_type(4)));
typedef float f32x4 __attribute__((ext_vector_type(4)));
typedef unsigned short u16;
typedef unsigned short u16x8 __attribute__((ext_vector_type(8)));

#define DIM 4096
#define NHEADS 32
#define NKV 8
#define HD 128
#define BB 2
#define SS 2048
#define MROWS (BB*SS)        // 4096
#define QKVP 6144            // fused QKV row pitch (4096 Q | 1024 K | 1024 V)
#define QSCALE 0.08838834764831843f  // 1/sqrt(128)

#define WAIT_LGKM0 asm volatile("s_waitcnt lgkmcnt(0)" ::: "memory")
#define WAIT_VM0   asm volatile("s_waitcnt vmcnt(0)" ::: "memory")
#define WAIT_VM4   asm volatile("s_waitcnt vmcnt(4)" ::: "memory")
#define WAIT_VM8   asm volatile("s_waitcnt vmcnt(8)" ::: "memory")
#define SGB0       __builtin_amdgcn_sched_barrier(0)

__device__ __forceinline__ u16 f2bf(float f) {
  unsigned int u = __float_as_uint(f);
  u += 0x7fffu + ((u >> 16) & 1u);   // round-to-nearest-even
  return (u16)(u >> 16);
}

__device__ __forceinline__ void gload16(const void* g, void* l) {
  __builtin_amdgcn_global_load_lds(
      (const __attribute__((address_space(1))) unsigned int*)g,
      (__attribute__((address_space(3))) unsigned int*)l, 16, 0, 0);
}

__device__ __forceinline__ bf16x4 tr16(const void* p) {
  bf16x4 d;
  asm volatile("ds_read_b64_tr_b16 %0, %1"
               : "=v"(d)
               : "v"((const __attribute__((address_space(3))) u16*)p)
               : "memory");
  return d;
}

template<int CTRL>
__device__ __forceinline__ float dpp_ror(float x) {
  return __int_as_float(__builtin_amdgcn_update_dpp(
      0, __float_as_int(x), CTRL, 0xF, 0xF, false));
}
__device__ __forceinline__ float red16_max(float v) {
  v = fmaxf(v, dpp_ror<0x121>(v));
  v = fmaxf(v, dpp_ror<0x122>(v));
  v = fmaxf(v, dpp_ror<0x124>(v));
  v = fmaxf(v, dpp_ror<0x128>(v));
  return v;
}
__device__ __forceinline__ float red16_sum(float v) {
  v += dpp_ror<0x121>(v);
  v += dpp_ror<0x122>(v);
  v += dpp_ror<0x124>(v);
  v += dpp_ror<0x128>(v);
  return v;
}

// ---------------- fp32 -> bf16 conversion, all 4 tensors in one launch ----------------
__global__ __launch_bounds__(256) void f2b4_kernel(
    const float* __restrict__ xa, const float* __restrict__ xb,
    const float* __restrict__ xc, const float* __restrict__ xd,
    u16* __restrict__ oa, u16* __restrict__ ob,
    u16* __restrict__ oc, u16* __restrict__ od) {
  int i = blockIdx.x * 256 + threadIdx.x;
  const float* in; u16* out; int k;
  if (i < 2097152)      { in = xa; out = oa; k = i; }
  else if (i < 4194304) { in = xb; out = ob; k = i - 2097152; }
  else if (i < 5242880) { in = xc; out = oc; k = i - 4194304; }
  else                  { in = xd; out = od; k = i - 5242880; }
  const float4* in4 = (const float4*)in;
  float4 a = in4[2*(size_t)k];
  float4 b = in4[2*(size_t)k + 1];
  u16x8 o;
  o[0]=f2bf(a.x); o[1]=f2bf(a.y); o[2]=f2bf(a.z); o[3]=f2bf(a.w);
  o[4]=f2bf(b.x); o[5]=f2bf(b.y); o[6]=f2bf(b.z); o[7]=f2bf(b.w);
  ((u16x8*)out)[k] = o;
}

// ---------------- 256x256 / BK=64 / 8-wave GEMM, C = A @ B^T ----------------
// B BYPASSES LDS: each wave loads its 64x64 B-subtile global->regs one tile
// ahead (lanes coalesce to 16x64B lines, L2-resident via XCD swizzle); B regs
// overwritten only after the MFMA cluster reads them (WAR by dataflow).
// A in LDS, 2 dbufs x 32KB (natural 128B rows = BK=64), both-sides XOR
// swizzle chunk^=(row&7). One barrier per K-tile. vmcnt discipline:
// WAIT_VM4 before MFMA pins B(i)+stage(i) landed (stage(i+1) in flight);
// WAIT_VM8 before barrier pins stage(i+1) (B(i+1) in flight) - never 0.
// WAR on dbuf: stage(i+1)->dbuf((i+1)&1) whose F_{i-1} reads retired before
// the barrier entering interval i.
template<int OUTF32>
__global__ __launch_bounds__(512, 2) void gemm256(
    const u16* __restrict__ A, const u16* __restrict__ Bm, void* __restrict__ C,
    int M, int N, int K, int nbx, int acut, float a0, float a1) {
  __shared__ char smem[65536];            // A dbufs: 2 x 32KB

  const int t = threadIdx.x;
  const int l = t & 63, w = t >> 6;
  const int l15 = l & 15, l4 = l >> 4;
  const int wm = w >> 2, wn = w & 3;      // 2 x 4 wave grid, wave-tile 128x64

  // bijective XCD swizzle (nwg % 8 == 0 for all our grids)
  const int nwg = gridDim.x;
  const int cpx = nwg >> 3;
  const int sw = (blockIdx.x & 7) * cpx + (blockIdx.x >> 3);
  const int bx = sw % nbx, by = sw / nbx;
  const int row0 = by * 256, col0 = bx * 256;
  const float alpha = (col0 < acut) ? a0 : a1;

  f32x4 acc[8][4] = {};

  // ---- A staging: unit u = i*512 + w*64 + l (16B units, 2048/tile)
  // ldsrow j = i*64 + w*8 + (l>>3); stored chunk (l&7) holds src chunk
  // cs = (l&7)^(l>>3)  (j&7 == (l>>3) since i*64, w*8 are mult of 8)
  const int jrow = w*8 + (l >> 3);
  const int csw  = (l & 7) ^ (l >> 3);
  const u16* pA = A + (size_t)(row0 + jrow) * K + csw * 8;
  char* const ldsw = (char*)smem + w*1024;   // +dbuf*32768 +i*8192; lane adds l*16

  auto stageA = [&](int tile) {
    const u16* s = pA + tile * 64;
    char* d = ldsw + (tile & 1) * 32768;
    gload16(s,                  d);
    gload16(s + (size_t)64*K,   d + 8192);
    gload16(s + (size_t)128*K,  d + 16384);
    gload16(s + (size_t)192*K,  d + 24576);
  };

  // ---- B direct-to-reg base: row (col0+wn*64+ni*16+l15), k = tile*64+kk*32+l4*8
  const u16* pB = Bm + (size_t)(col0 + wn*64 + l15) * K + l4 * 8;
  const size_t bstride = (size_t)16 * K;   // ni step (elements)

  bf16x8 Ar[8][2], Br[4][2];

  auto loadB = [&](int tile) {
    const u16* s = pB + tile * 64;
    #pragma unroll
    for (int ni = 0; ni < 4; ++ni) {
      Br[ni][0] = *(const bf16x8*)(s + (size_t)ni * bstride);
      Br[ni][1] = *(const bf16x8*)(s + (size_t)ni * bstride + 32);
    }
  };

  // ---- A fragment read offsets (both-sides swizzle; r&7 == l15&7) ----
  const int cxk0 = ((0*4 + l4) ^ (l15 & 7)) * 16;
  const int cxk1 = ((1*4 + l4) ^ (l15 & 7)) * 16;
  const int abase = wm*16384 + l15*128;

  auto rdA = [&](int dbuf) {
    const char* Ab = (const char*)smem + dbuf*32768 + abase;
    #pragma unroll
    for (int mi = 0; mi < 8; ++mi) {
      Ar[mi][0] = *(const bf16x8*)(Ab + mi*2048 + cxk0);
      Ar[mi][1] = *(const bf16x8*)(Ab + mi*2048 + cxk1);
    }
  };

  auto mfma64 = [&]() {
    __builtin_amdgcn_s_setprio(1);
    #pragma unroll
    for (int kk = 0; kk < 2; ++kk)
      #pragma unroll
      for (int mi = 0; mi < 8; ++mi)
        #pragma unroll
        for (int ni = 0; ni < 4; ++ni)
          acc[mi][ni] = __builtin_amdgcn_mfma_f32_16x16x32_bf16(
              Ar[mi][kk], Br[ni][kk], acc[mi][ni], 0, 0, 0);
    __builtin_amdgcn_s_setprio(0);
  };

  const int nt = K >> 6;                  // K-tiles of 64

  // prologue: tile 0 staged + B(0) loaded, all landed
  stageA(0);
  loadB(0);
  WAIT_VM0;
  __builtin_amdgcn_s_barrier();

  for (int i = 0; i < nt - 1; ++i) {
    rdA(i & 1);                  // 16 x ds_read_b128 (A only)
    stageA(i + 1);               // 4 x gload16 -> other dbuf (WAR-safe)
    WAIT_VM4;                    // B(i) + stage(i) landed; stage(i+1) flies
    WAIT_LGKM0; SGB0;            // A frags ready (rule 18 fence)
    mfma64();                    // 64 MFMA consume Ar x Br
    loadB(i + 1);                // overwrite Br AFTER cluster (WAR dataflow)
    WAIT_VM8;                    // stage(i+1) landed; B(i+1) flies
    __builtin_amdgcn_s_barrier();
  }
  // peeled last tile
  rdA((nt - 1) & 1);
  WAIT_VM0;                      // B(nt-1) landed
  WAIT_LGKM0; SGB0;
  mfma64();

  // epilogue: C/D layout col=lane&15, row=(lane>>4)*4+reg
  #pragma unroll
  for (int mi = 0; mi < 8; ++mi) {
    #pragma unroll
    for (int ni = 0; ni < 4; ++ni) {
      #pragma unroll
      for (int r = 0; r < 4; ++r) {
        size_t rr = (size_t)(row0 + wm*128 + mi*16 + l4*4 + r);
        size_t cc = (size_t)(col0 + wn*64 + ni*16 + l15);
        float v = acc[mi][ni][r] * alpha;
        if (OUTF32) ((float*)C)[rr*(size_t)N + cc] = v;
        else        ((u16*)C)[rr*(size_t)N + cc] = f2bf(v);
      }
    }
  }
}

// ---------------- causal GQA flash attention (QKVP pitch) ----------------
__global__ __launch_bounds__(256, 2) void attn_kernel(
    const u16* __restrict__ QKV,  // [4096][6144]: 0..4095 Q | 4096..5119 K | 5120..6143 V
    u16* __restrict__ O) {        // [4096][4096]
  __shared__ u16 Ks[2][64*128];
  __shared__ u16 Vs[2][64*128];
  __shared__ u16 Ps[4][1024];
  const int t = threadIdx.x;
  const int l = t & 63, w = t >> 6;
  const int l15 = l & 15, l4 = l >> 4;
  const int pair = blockIdx.x, h = blockIdx.y, b = blockIdx.z;
  const int hkv = h >> 2;
  const u16* Kg = QKV + (size_t)(b*SS) * QKVP + DIM + hkv*HD;
  const u16* Vg = Kg + NKV*HD;
  u16* Pw = &Ps[w][0];

  auto stage = [&](u16* Ksb, u16* Vsb, int kv0) {
    const u16* Kr = Kg + (size_t)kv0 * QKVP;
    const u16* Vr = Vg + (size_t)kv0 * QKVP;
    #pragma unroll
    for (int i = 0; i < 4; ++i) {
      int o = i*4096 + w*1024 + l*16;
      int row = o >> 8;
      int sc = l15 ^ (row & 7);
      gload16((const char*)(Kr + (size_t)row * QKVP) + sc*16,
              (char*)Ksb + i*4096 + w*1024);
    }
    #pragma unroll
    for (int i = 0; i < 4; ++i) {
      int cb = i*4 + w;
      int kv = cb*4 + ((l & 7) >> 1);
      int d0 = ((l >> 3) << 4) + (l & 1)*8;
      gload16((const char*)(Vr + (size_t)kv * QKVP + d0),
              (char*)Vsb + cb*1024);
    }
  };

  for (int half = 0; half < 2; ++half) {
    const int qb = half ? (15 - pair) : pair;
    const int q0 = qb * 128;
    const int q0w = q0 + w*32;

    const size_t qbase = ((size_t)(b*SS + q0w)) * QKVP + h*HD;
    bf16x8 qf[2][4];
    #pragma unroll
    for (int m = 0; m < 2; ++m)
      #pragma unroll
      for (int kd = 0; kd < 4; ++kd)
        qf[m][kd] = *(const bf16x8*)&QKV[qbase + (size_t)(m*16 + l15)*QKVP + kd*32 + l4*8];

    f32x4 oacc[2][8] = {};
    float mrun[2][4], lrun[2][4];
    #pragma unroll
    for (int m = 0; m < 2; ++m)
      #pragma unroll
      for (int r = 0; r < 4; ++r) { mrun[m][r] = -1e30f; lrun[m][r] = 0.f; }

    const int nst = 2*qb + 2;
    stage(Ks[0], Vs[0], 0);
    WAIT_VM0;
    __builtin_amdgcn_s_barrier();
    SGB0;

    for (int st = 0; st < nst; ++st) {
      const int kv0 = st * 64;
      u16* Ksb = Ks[st & 1];
      u16* Vsb = Vs[st & 1];
      if (st + 1 < nst) stage(Ks[(st+1) & 1], Vs[(st+1) & 1], kv0 + 64);

      if (kv0 <= q0w + 31) {
        f32x4 sacc[2][4] = {};
        __builtin_amdgcn_s_setprio(1);
        #pragma unroll
        for (int kd = 0; kd < 4; ++kd) {
          bf16x8 kf[4];
          #pragma unroll
          for (int n = 0; n < 4; ++n) {
            int row = n*16 + l15;
            int off = (row << 8) | (((kd*4 + l4) ^ (row & 7)) << 4);
            kf[n] = *(const bf16x8*)((const char*)Ksb + off);
          }
          #pragma unroll
          for (int m = 0; m < 2; ++m)
            #pragma unroll
            for (int n = 0; n < 4; ++n)
              sacc[m][n] = __builtin_amdgcn_mfma_f32_16x16x32_bf16(qf[m][kd], kf[n], sacc[m][n], 0, 0, 0);
        }
        __builtin_amdgcn_s_setprio(0);

        if (st >= 2*qb) {
          #pragma unroll
          for (int n = 0; n < 4; ++n) {
            int ki = kv0 + n*16 + l15;
            #pragma unroll
            for (int m = 0; m < 2; ++m)
              #pragma unroll
              for (int r = 0; r < 4; ++r) {
                int qi = q0w + m*16 + l4*4 + r;
                if (ki > qi) sacc[m][n][r] = -1e30f;
              }
          }
        }

        float pr[2][4][4];
        #pragma unroll
        for (int m = 0; m < 2; ++m) {
          #pragma unroll
          for (int r = 0; r < 4; ++r) {
            float s0 = sacc[m][0][r], s1 = sacc[m][1][r];
            float s2 = sacc[m][2][r], s3 = sacc[m][3][r];
            float vm = fmaxf(fmaxf(s0, s1), fmaxf(s2, s3));
            vm = red16_max(vm);
            float mo = mrun[m][r];
            float mnew = fmaxf(mo, vm);
            float al = __expf(mo - mnew);
            float p0 = __expf(s0 - mnew), p1 = __expf(s1 - mnew);
            float p2 = __expf(s2 - mnew), p3 = __expf(s3 - mnew);
            float rs = red16_sum((p0 + p1) + (p2 + p3));
            mrun[m][r] = mnew;
            lrun[m][r] = lrun[m][r]*al + rs;
            #pragma unroll
            for (int dn = 0; dn < 8; ++dn) oacc[m][dn][r] *= al;
            pr[m][r][0] = p0; pr[m][r][1] = p1; pr[m][r][2] = p2; pr[m][r][3] = p3;
          }
        }

        #pragma unroll
        for (int kvh = 0; kvh < 2; ++kvh) {
          #pragma unroll
          for (int m = 0; m < 2; ++m)
            #pragma unroll
            for (int nn = 0; nn < 2; ++nn) {
              int n = kvh*2 + nn;
              bf16x4 w4;
              w4[0] = (__bf16)pr[m][0][n]; w4[1] = (__bf16)pr[m][1][n];
              w4[2] = (__bf16)pr[m][2][n]; w4[3] = (__bf16)pr[m][3][n];
              *(bf16x4*)((char*)Pw + ((nn*4 + (l15 >> 2))*2 + m)*128
                                   + (l15 & 3)*32 + l4*8) = w4;
            }
          const char* pb = (const char*)Pw + l4*512 + l15*8;
          bf16x4 a00 = tr16(pb);
          bf16x4 a01 = tr16(pb + 256);
          bf16x4 a10 = tr16(pb + 128);
          bf16x4 a11 = tr16(pb + 384);
          const char* vb = (const char*)Vsb + l4*2048 + l15*8 + kvh*8192;
          bf16x4 b0[8], b1[8];
          #pragma unroll
          for (int dn = 0; dn < 8; ++dn) {
            b0[dn] = tr16(vb + dn*128);
            b1[dn] = tr16(vb + dn*128 + 1024);
          }
          WAIT_LGKM0; SGB0;
          bf16x8 pa0 = __builtin_shufflevector(a00, a01, 0,1,2,3,4,5,6,7);
          bf16x8 pa1 = __builtin_shufflevector(a10, a11, 0,1,2,3,4,5,6,7);
          __builtin_amdgcn_s_setprio(1);
          #pragma unroll
          for (int dn = 0; dn < 8; ++dn) {
            bf16x8 v8 = __builtin_shufflevector(b0[dn], b1[dn], 0,1,2,3,4,5,6,7);
            oacc[0][dn] = __builtin_amdgcn_mfma_f32_16x16x32_bf16(pa0, v8, oacc[0][dn], 0, 0, 0);
            oacc[1][dn] = __builtin_amdgcn_mfma_f32_16x16x32_bf16(pa1, v8, oacc[1][dn], 0, 0, 0);
          }
          __builtin_amdgcn_s_setprio(0);
        }
      }

      WAIT_VM0;
      __builtin_amdgcn_s_barrier();
      SGB0;
    }

    const size_t obase = ((size_t)(b*SS + q0w)) * DIM + h*HD;
    #pragma unroll
    for (int m = 0; m < 2; ++m) {
      #pragma unroll
      for (int r = 0; r < 4; ++r) {
        float inv = 1.0f / lrun[m][r];
        int srow = m*16 + l4*4 + r;
        #pragma unroll
        for (int dn = 0; dn < 8; ++dn)
          O[obase + (size_t)srow*DIM + dn*16 + l15] = f2bf(oacc[m][dn][r] * inv);
      }
    }
  }
}

extern "C" void kernel_launch(void* const* d_in, const int* in_sizes, int n_in,
                              void* d_out, int out_size, void* d_ws, size_t ws_size,
                              hipStream_t stream) {
  const float* x   = (const float*)d_in[0];
  const float* Wq  = (const float*)d_in[1];
  const float* Wkv = (const float*)d_in[2];
  const float* Wo  = (const float*)d_in[3];

  if (ws_size < (160ull << 20)) return;
  char* ws = (char*)d_ws;
  u16* xb   = (u16*)(ws);                  // 32 MB [4096][4096]
  u16* Wqb  = (u16*)(ws + (32ull  << 20)); // 32 MB [4096][4096]  \ fused W rows 0..6143
  u16* Wkvb = (u16*)(ws + (64ull  << 20)); // 16 MB [2048][4096]  /
  u16* Wob  = (u16*)(ws + (80ull  << 20)); // 32 MB [4096][4096]
  u16* QKVb = (u16*)(ws + (112ull << 20)); // 48 MB [4096][6144]
  u16* attnb = xb;                         // alias after projections

  // fp32 -> bf16, one launch (x | Wq | Wkv | Wo)
  f2b4_kernel<<<28672, 256, 0, stream>>>(x, Wq, Wkv, Wo, xb, Wqb, Wkvb, Wob);

  // fused QKV projection: [4096][6144] = xb @ [Wq;Wkv]^T ; QSCALE on Q cols only
  gemm256<0><<<dim3(16*24), 512, 0, stream>>>(xb, Wqb, QKVb,
                                              MROWS, QKVP, DIM, 24, DIM, QSCALE, 1.0f);

  attn_kernel<<<dim3(8, NHEADS, BB), 256, 0, stream>>>(QKVb, attnb);

  // output projection (fp32 out)
  gemm256<1><<<dim3(16*16), 512, 0, stream>>>(attnb, Wob, d_out,
                                              MROWS, DIM, DIM, 16, 0, 1.0f, 1.0f);
}

// Round 12
// 541.903 us; speedup vs baseline: 1.2767x; 1.2767x over previous
//
#include <hip/hip_runtime.h>

typedef __bf16 bf16x8 __attribute__((ext_vector_type(8)));
typedef __bf16 bf16x4 __attribute__((ext_vector_type(4)));
typedef float f32x4 __attribute__((ext_vector_type(4)));
typedef unsigned short u16;
typedef unsigned short u16x8 __attribute__((ext_vector_type(8)));

#define DIM 4096
#define NHEADS 32
#define NKV 8
#define HD 128
#define BB 2
#define SS 2048
#define MROWS (BB*SS)        // 4096
#define QKVP 6144            // fused QKV row pitch (4096 Q | 1024 K | 1024 V)
#define QSCALE 0.08838834764831843f  // 1/sqrt(128)

#define WAIT_LGKM0 asm volatile("s_waitcnt lgkmcnt(0)" ::: "memory")
#define WAIT_VM0   asm volatile("s_waitcnt vmcnt(0)" ::: "memory")
#define WAIT_VM6   asm volatile("s_waitcnt vmcnt(6)" ::: "memory")
#define SGB0       __builtin_amdgcn_sched_barrier(0)

__device__ __forceinline__ u16 f2bf(float f) {
  unsigned int u = __float_as_uint(f);
  u += 0x7fffu + ((u >> 16) & 1u);   // round-to-nearest-even
  return (u16)(u >> 16);
}

__device__ __forceinline__ void gload16(const void* g, void* l) {
  __builtin_amdgcn_global_load_lds(
      (const __attribute__((address_space(1))) unsigned int*)g,
      (__attribute__((address_space(3))) unsigned int*)l, 16, 0, 0);
}

__device__ __forceinline__ bf16x4 tr16(const void* p) {
  bf16x4 d;
  asm volatile("ds_read_b64_tr_b16 %0, %1"
               : "=v"(d)
               : "v"((const __attribute__((address_space(3))) u16*)p)
               : "memory");
  return d;
}

template<int CTRL>
__device__ __forceinline__ float dpp_ror(float x) {
  return __int_as_float(__builtin_amdgcn_update_dpp(
      0, __float_as_int(x), CTRL, 0xF, 0xF, false));
}
__device__ __forceinline__ float red16_max(float v) {
  v = fmaxf(v, dpp_ror<0x121>(v));
  v = fmaxf(v, dpp_ror<0x122>(v));
  v = fmaxf(v, dpp_ror<0x124>(v));
  v = fmaxf(v, dpp_ror<0x128>(v));
  return v;
}
__device__ __forceinline__ float red16_sum(float v) {
  v += dpp_ror<0x121>(v);
  v += dpp_ror<0x122>(v);
  v += dpp_ror<0x124>(v);
  v += dpp_ror<0x128>(v);
  return v;
}

// ---------------- fp32 -> bf16 conversion, all 4 tensors in one launch ----------------
__global__ __launch_bounds__(256) void f2b4_kernel(
    const float* __restrict__ xa, const float* __restrict__ xb,
    const float* __restrict__ xc, const float* __restrict__ xd,
    u16* __restrict__ oa, u16* __restrict__ ob,
    u16* __restrict__ oc, u16* __restrict__ od) {
  int i = blockIdx.x * 256 + threadIdx.x;
  const float* in; u16* out; int k;
  if (i < 2097152)      { in = xa; out = oa; k = i; }
  else if (i < 4194304) { in = xb; out = ob; k = i - 2097152; }
  else if (i < 5242880) { in = xc; out = oc; k = i - 4194304; }
  else                  { in = xd; out = od; k = i - 5242880; }
  const float4* in4 = (const float4*)in;
  float4 a = in4[2*(size_t)k];
  float4 b = in4[2*(size_t)k + 1];
  u16x8 o;
  o[0]=f2bf(a.x); o[1]=f2bf(a.y); o[2]=f2bf(a.z); o[3]=f2bf(a.w);
  o[4]=f2bf(b.x); o[5]=f2bf(b.y); o[6]=f2bf(b.z); o[7]=f2bf(b.w);
  ((u16x8*)out)[k] = o;
}

// ---------------- 256x128 / BK=32 / 4-wave GEMM, C = A @ B^T ----------------
// R9 schedule (reg-dbuf + counted vmcnt, best measured) at 2-blocks/CU
// geometry: 72KB LDS (3-ring x 24KB), 256 threads. Mechanism under test:
// resident-block independence (O-proj 573 TF @1/CU vs QKV 866 @1.5/CU with
// identical code => perf tracks resident blocks). Ring-3 validity: live bufs
// at step i are {i+1 (ds-read), i+2 (landed), i+3 (in flight -> buf i%3,
// whose reads retired at step i-1's lgkm0+barrier)}. Counted invariant:
// entering step i, stage(i+1) landed (prev step's VM6), stage(i+2) in
// flight (6 loads). LDS per buf: A 16KB @0, B 8KB @16384; ldsrow j (128B)
// holds tile rows {2j,2j+1}; stored 16B-chunk c = src chunk ^ (j&7).
template<int OUTF32>
__global__ __launch_bounds__(256, 2) void gemm256(
    const u16* __restrict__ A, const u16* __restrict__ Bm, void* __restrict__ C,
    int M, int N, int K, int nbx, int acut, float a0, float a1) {
  __shared__ char smem[73728];            // 3 bufs x 24576

  const int t = threadIdx.x;
  const int l = t & 63, w = t >> 6;
  const int l15 = l & 15, l4 = l >> 4;
  const int wm = w >> 1, wn = w & 1;      // 2 x 2 wave grid, wave-tile 128x64

  // bijective XCD swizzle (nwg % 8 == 0 for all our grids)
  const int nwg = gridDim.x;
  const int cpx = nwg >> 3;
  const int sw = (blockIdx.x & 7) * cpx + (blockIdx.x >> 3);
  const int bx = sw % nbx, by = sw / nbx;
  const int row0 = by * 256, col0 = bx * 128;
  const float alpha = (col0 < acut) ? a0 : a1;

  f32x4 acc[8][4] = {};

  // ---- stage addressing: A = 1024 16B-units (thread t: q*256+t, q=0..3),
  // B = 512 units (q=0..1). unit u: ldsrow j=u>>3, stored chunk u&7 holds
  // source chunk cs=(u&7)^(j&7); tile row r=2j+(cs>>2), k-off kc=(cs&3)*8.
  const u16* pA0; const u16* pA1; const u16* pA2; const u16* pA3;
  const u16* pB0; const u16* pB1;
  {
    int u, j, cs, r, kc;
    u = t;          j = u >> 3; cs = (u & 7) ^ (j & 7); r = 2*j + (cs >> 2); kc = (cs & 3)*8;
    pA0 = A + (size_t)(row0 + r) * K + kc;
    u = t + 256;    j = u >> 3; cs = (u & 7) ^ (j & 7); r = 2*j + (cs >> 2); kc = (cs & 3)*8;
    pA1 = A + (size_t)(row0 + r) * K + kc;
    u = t + 512;    j = u >> 3; cs = (u & 7) ^ (j & 7); r = 2*j + (cs >> 2); kc = (cs & 3)*8;
    pA2 = A + (size_t)(row0 + r) * K + kc;
    u = t + 768;    j = u >> 3; cs = (u & 7) ^ (j & 7); r = 2*j + (cs >> 2); kc = (cs & 3)*8;
    pA3 = A + (size_t)(row0 + r) * K + kc;
    u = t;          j = u >> 3; cs = (u & 7) ^ (j & 7); r = 2*j + (cs >> 2); kc = (cs & 3)*8;
    pB0 = Bm + (size_t)(col0 + r) * K + kc;
    u = t + 256;    j = u >> 3; cs = (u & 7) ^ (j & 7); r = 2*j + (cs >> 2); kc = (cs & 3)*8;
    pB1 = Bm + (size_t)(col0 + r) * K + kc;
  }

  auto stage = [&](int tile, int buf) {
    char* d = (char*)smem + buf * 24576 + w*1024;
    const int k0 = tile * 32;
    gload16(pA0 + k0, d);
    gload16(pA1 + k0, d + 4096);
    gload16(pA2 + k0, d + 8192);
    gload16(pA3 + k0, d + 12288);
    gload16(pB0 + k0, d + 16384);
    gload16(pB1 + k0, d + 20480);
  };

  // ---- fragment offsets (swizzle is mi/ni-invariant: step 1024 B) ----
  int offA0, offB0;
  {
    int r = wm*128 + l15, j = r >> 1;
    int c = ((r & 1)*4 + l4) ^ (j & 7);
    offA0 = j*128 + c*16;
    r = wn*64 + l15; j = r >> 1;
    c = ((r & 1)*4 + l4) ^ (j & 7);
    offB0 = 16384 + j*128 + c*16;
  }

  struct Frags { bf16x8 a0,a1,a2,a3,a4,a5,a6,a7,b0,b1,b2,b3; };
  Frags F0, F1;

  auto loadF = [&](Frags& F, int buf) {
    const char* Sb = (const char*)smem + buf * 24576;
    const char* Ab = Sb + offA0;
    const char* Bb = Sb + offB0;
    F.a0 = *(const bf16x8*)(Ab);
    F.a1 = *(const bf16x8*)(Ab + 1024);
    F.a2 = *(const bf16x8*)(Ab + 2048);
    F.a3 = *(const bf16x8*)(Ab + 3072);
    F.a4 = *(const bf16x8*)(Ab + 4096);
    F.a5 = *(const bf16x8*)(Ab + 5120);
    F.a6 = *(const bf16x8*)(Ab + 6144);
    F.a7 = *(const bf16x8*)(Ab + 7168);
    F.b0 = *(const bf16x8*)(Bb);
    F.b1 = *(const bf16x8*)(Bb + 1024);
    F.b2 = *(const bf16x8*)(Bb + 2048);
    F.b3 = *(const bf16x8*)(Bb + 3072);
  };

  auto mfmaC = [&](const Frags& F) {
    __builtin_amdgcn_s_setprio(1);
    acc[0][0] = __builtin_amdgcn_mfma_f32_16x16x32_bf16(F.a0, F.b0, acc[0][0], 0, 0, 0);
    acc[0][1] = __builtin_amdgcn_mfma_f32_16x16x32_bf16(F.a0, F.b1, acc[0][1], 0, 0, 0);
    acc[0][2] = __builtin_amdgcn_mfma_f32_16x16x32_bf16(F.a0, F.b2, acc[0][2], 0, 0, 0);
    acc[0][3] = __builtin_amdgcn_mfma_f32_16x16x32_bf16(F.a0, F.b3, acc[0][3], 0, 0, 0);
    acc[1][0] = __builtin_amdgcn_mfma_f32_16x16x32_bf16(F.a1, F.b0, acc[1][0], 0, 0, 0);
    acc[1][1] = __builtin_amdgcn_mfma_f32_16x16x32_bf16(F.a1, F.b1, acc[1][1], 0, 0, 0);
    acc[1][2] = __builtin_amdgcn_mfma_f32_16x16x32_bf16(F.a1, F.b2, acc[1][2], 0, 0, 0);
    acc[1][3] = __builtin_amdgcn_mfma_f32_16x16x32_bf16(F.a1, F.b3, acc[1][3], 0, 0, 0);
    acc[2][0] = __builtin_amdgcn_mfma_f32_16x16x32_bf16(F.a2, F.b0, acc[2][0], 0, 0, 0);
    acc[2][1] = __builtin_amdgcn_mfma_f32_16x16x32_bf16(F.a2, F.b1, acc[2][1], 0, 0, 0);
    acc[2][2] = __builtin_amdgcn_mfma_f32_16x16x32_bf16(F.a2, F.b2, acc[2][2], 0, 0, 0);
    acc[2][3] = __builtin_amdgcn_mfma_f32_16x16x32_bf16(F.a2, F.b3, acc[2][3], 0, 0, 0);
    acc[3][0] = __builtin_amdgcn_mfma_f32_16x16x32_bf16(F.a3, F.b0, acc[3][0], 0, 0, 0);
    acc[3][1] = __builtin_amdgcn_mfma_f32_16x16x32_bf16(F.a3, F.b1, acc[3][1], 0, 0, 0);
    acc[3][2] = __builtin_amdgcn_mfma_f32_16x16x32_bf16(F.a3, F.b2, acc[3][2], 0, 0, 0);
    acc[3][3] = __builtin_amdgcn_mfma_f32_16x16x32_bf16(F.a3, F.b3, acc[3][3], 0, 0, 0);
    acc[4][0] = __builtin_amdgcn_mfma_f32_16x16x32_bf16(F.a4, F.b0, acc[4][0], 0, 0, 0);
    acc[4][1] = __builtin_amdgcn_mfma_f32_16x16x32_bf16(F.a4, F.b1, acc[4][1], 0, 0, 0);
    acc[4][2] = __builtin_amdgcn_mfma_f32_16x16x32_bf16(F.a4, F.b2, acc[4][2], 0, 0, 0);
    acc[4][3] = __builtin_amdgcn_mfma_f32_16x16x32_bf16(F.a4, F.b3, acc[4][3], 0, 0, 0);
    acc[5][0] = __builtin_amdgcn_mfma_f32_16x16x32_bf16(F.a5, F.b0, acc[5][0], 0, 0, 0);
    acc[5][1] = __builtin_amdgcn_mfma_f32_16x16x32_bf16(F.a5, F.b1, acc[5][1], 0, 0, 0);
    acc[5][2] = __builtin_amdgcn_mfma_f32_16x16x32_bf16(F.a5, F.b2, acc[5][2], 0, 0, 0);
    acc[5][3] = __builtin_amdgcn_mfma_f32_16x16x32_bf16(F.a5, F.b3, acc[5][3], 0, 0, 0);
    acc[6][0] = __builtin_amdgcn_mfma_f32_16x16x32_bf16(F.a6, F.b0, acc[6][0], 0, 0, 0);
    acc[6][1] = __builtin_amdgcn_mfma_f32_16x16x32_bf16(F.a6, F.b1, acc[6][1], 0, 0, 0);
    acc[6][2] = __builtin_amdgcn_mfma_f32_16x16x32_bf16(F.a6, F.b2, acc[6][2], 0, 0, 0);
    acc[6][3] = __builtin_amdgcn_mfma_f32_16x16x32_bf16(F.a6, F.b3, acc[6][3], 0, 0, 0);
    acc[7][0] = __builtin_amdgcn_mfma_f32_16x16x32_bf16(F.a7, F.b0, acc[7][0], 0, 0, 0);
    acc[7][1] = __builtin_amdgcn_mfma_f32_16x16x32_bf16(F.a7, F.b1, acc[7][1], 0, 0, 0);
    acc[7][2] = __builtin_amdgcn_mfma_f32_16x16x32_bf16(F.a7, F.b2, acc[7][2], 0, 0, 0);
    acc[7][3] = __builtin_amdgcn_mfma_f32_16x16x32_bf16(F.a7, F.b3, acc[7][3], 0, 0, 0);
    __builtin_amdgcn_s_setprio(0);
  };

  const int nt = K >> 5;                  // K-tiles of 32 (even)

  // prologue: 3 tiles in flight; tiles 0,1 landed (VM6); regs for tile 0
  stage(0, 0); stage(1, 1); stage(2, 2);
  WAIT_VM6;
  __builtin_amdgcn_s_barrier();
  loadF(F0, 0);
  WAIT_LGKM0; SGB0;

  int b3 = 0;                             // buf of current tile ( = i%3 )
  for (int i = 0; i < nt; i += 2) {
    {
      if (i + 3 < nt) stage(i + 3, b3);   // (i+3)%3 == i%3: WAR-safe
      const int bn = (b3 == 2) ? 0 : b3 + 1;
      if (i + 1 < nt) loadF(F1, bn);      // stage(i+1) landed (invariant)
      SGB0;
      mfmaC(F0);
      WAIT_LGKM0; SGB0;
      if (i + 3 < nt) { WAIT_VM6; } else { WAIT_VM0; }  // stage(i+2) landed
      __builtin_amdgcn_s_barrier();
      b3 = bn;
    }
    if (i + 1 < nt) {
      if (i + 4 < nt) stage(i + 4, b3);
      const int bn = (b3 == 2) ? 0 : b3 + 1;
      if (i + 2 < nt) loadF(F0, bn);
      SGB0;
      mfmaC(F1);
      WAIT_LGKM0; SGB0;
      if (i + 4 < nt) { WAIT_VM6; } else { WAIT_VM0; }
      __builtin_amdgcn_s_barrier();
      b3 = bn;
    }
  }

  // epilogue: C/D layout col=lane&15, row=(lane>>4)*4+reg
  #pragma unroll
  for (int mi = 0; mi < 8; ++mi) {
    #pragma unroll
    for (int ni = 0; ni < 4; ++ni) {
      #pragma unroll
      for (int r = 0; r < 4; ++r) {
        size_t rr = (size_t)(row0 + wm*128 + mi*16 + l4*4 + r);
        size_t cc = (size_t)(col0 + wn*64 + ni*16 + l15);
        float v = acc[mi][ni][r] * alpha;
        if (OUTF32) ((float*)C)[rr*(size_t)N + cc] = v;
        else        ((u16*)C)[rr*(size_t)N + cc] = f2bf(v);
      }
    }
  }
}

// ---------------- causal GQA flash attention (QKVP pitch) ----------------
__global__ __launch_bounds__(256, 2) void attn_kernel(
    const u16* __restrict__ QKV,  // [4096][6144]: 0..4095 Q | 4096..5119 K | 5120..6143 V
    u16* __restrict__ O) {        // [4096][4096]
  __shared__ u16 Ks[2][64*128];
  __shared__ u16 Vs[2][64*128];
  __shared__ u16 Ps[4][1024];
  const int t = threadIdx.x;
  const int l = t & 63, w = t >> 6;
  const int l15 = l & 15, l4 = l >> 4;
  const int pair = blockIdx.x, h = blockIdx.y, b = blockIdx.z;
  const int hkv = h >> 2;
  const u16* Kg = QKV + (size_t)(b*SS) * QKVP + DIM + hkv*HD;
  const u16* Vg = Kg + NKV*HD;
  u16* Pw = &Ps[w][0];

  auto stage = [&](u16* Ksb, u16* Vsb, int kv0) {
    const u16* Kr = Kg + (size_t)kv0 * QKVP;
    const u16* Vr = Vg + (size_t)kv0 * QKVP;
    #pragma unroll
    for (int i = 0; i < 4; ++i) {
      int o = i*4096 + w*1024 + l*16;
      int row = o >> 8;
      int sc = l15 ^ (row & 7);
      gload16((const char*)(Kr + (size_t)row * QKVP) + sc*16,
              (char*)Ksb + i*4096 + w*1024);
    }
    #pragma unroll
    for (int i = 0; i < 4; ++i) {
      int cb = i*4 + w;
      int kv = cb*4 + ((l & 7) >> 1);
      int d0 = ((l >> 3) << 4) + (l & 1)*8;
      gload16((const char*)(Vr + (size_t)kv * QKVP + d0),
              (char*)Vsb + cb*1024);
    }
  };

  for (int half = 0; half < 2; ++half) {
    const int qb = half ? (15 - pair) : pair;
    const int q0 = qb * 128;
    const int q0w = q0 + w*32;

    const size_t qbase = ((size_t)(b*SS + q0w)) * QKVP + h*HD;
    bf16x8 qf[2][4];
    #pragma unroll
    for (int m = 0; m < 2; ++m)
      #pragma unroll
      for (int kd = 0; kd < 4; ++kd)
        qf[m][kd] = *(const bf16x8*)&QKV[qbase + (size_t)(m*16 + l15)*QKVP + kd*32 + l4*8];

    f32x4 oacc[2][8] = {};
    float mrun[2][4], lrun[2][4];
    #pragma unroll
    for (int m = 0; m < 2; ++m)
      #pragma unroll
      for (int r = 0; r < 4; ++r) { mrun[m][r] = -1e30f; lrun[m][r] = 0.f; }

    const int nst = 2*qb + 2;
    stage(Ks[0], Vs[0], 0);
    WAIT_VM0;
    __builtin_amdgcn_s_barrier();
    SGB0;

    for (int st = 0; st < nst; ++st) {
      const int kv0 = st * 64;
      u16* Ksb = Ks[st & 1];
      u16* Vsb = Vs[st & 1];
      if (st + 1 < nst) stage(Ks[(st+1) & 1], Vs[(st+1) & 1], kv0 + 64);

      if (kv0 <= q0w + 31) {
        f32x4 sacc[2][4] = {};
        __builtin_amdgcn_s_setprio(1);
        #pragma unroll
        for (int kd = 0; kd < 4; ++kd) {
          bf16x8 kf[4];
          #pragma unroll
          for (int n = 0; n < 4; ++n) {
            int row = n*16 + l15;
            int off = (row << 8) | (((kd*4 + l4) ^ (row & 7)) << 4);
            kf[n] = *(const bf16x8*)((const char*)Ksb + off);
          }
          #pragma unroll
          for (int m = 0; m < 2; ++m)
            #pragma unroll
            for (int n = 0; n < 4; ++n)
              sacc[m][n] = __builtin_amdgcn_mfma_f32_16x16x32_bf16(qf[m][kd], kf[n], sacc[m][n], 0, 0, 0);
        }
        __builtin_amdgcn_s_setprio(0);

        if (st >= 2*qb) {
          #pragma unroll
          for (int n = 0; n < 4; ++n) {
            int ki = kv0 + n*16 + l15;
            #pragma unroll
            for (int m = 0; m < 2; ++m)
              #pragma unroll
              for (int r = 0; r < 4; ++r) {
                int qi = q0w + m*16 + l4*4 + r;
                if (ki > qi) sacc[m][n][r] = -1e30f;
              }
          }
        }

        float pr[2][4][4];
        #pragma unroll
        for (int m = 0; m < 2; ++m) {
          #pragma unroll
          for (int r = 0; r < 4; ++r) {
            float s0 = sacc[m][0][r], s1 = sacc[m][1][r];
            float s2 = sacc[m][2][r], s3 = sacc[m][3][r];
            float vm = fmaxf(fmaxf(s0, s1), fmaxf(s2, s3));
            vm = red16_max(vm);
            float mo = mrun[m][r];
            float mnew = fmaxf(mo, vm);
            float al = __expf(mo - mnew);
            float p0 = __expf(s0 - mnew), p1 = __expf(s1 - mnew);
            float p2 = __expf(s2 - mnew), p3 = __expf(s3 - mnew);
            float rs = red16_sum((p0 + p1) + (p2 + p3));
            mrun[m][r] = mnew;
            lrun[m][r] = lrun[m][r]*al + rs;
            #pragma unroll
            for (int dn = 0; dn < 8; ++dn) oacc[m][dn][r] *= al;
            pr[m][r][0] = p0; pr[m][r][1] = p1; pr[m][r][2] = p2; pr[m][r][3] = p3;
          }
        }

        #pragma unroll
        for (int kvh = 0; kvh < 2; ++kvh) {
          #pragma unroll
          for (int m = 0; m < 2; ++m)
            #pragma unroll
            for (int nn = 0; nn < 2; ++nn) {
              int n = kvh*2 + nn;
              bf16x4 w4;
              w4[0] = (__bf16)pr[m][0][n]; w4[1] = (__bf16)pr[m][1][n];
              w4[2] = (__bf16)pr[m][2][n]; w4[3] = (__bf16)pr[m][3][n];
              *(bf16x4*)((char*)Pw + ((nn*4 + (l15 >> 2))*2 + m)*128
                                   + (l15 & 3)*32 + l4*8) = w4;
            }
          const char* pb = (const char*)Pw + l4*512 + l15*8;
          bf16x4 a00 = tr16(pb);
          bf16x4 a01 = tr16(pb + 256);
          bf16x4 a10 = tr16(pb + 128);
          bf16x4 a11 = tr16(pb + 384);
          const char* vb = (const char*)Vsb + l4*2048 + l15*8 + kvh*8192;
          bf16x4 b0[8], b1[8];
          #pragma unroll
          for (int dn = 0; dn < 8; ++dn) {
            b0[dn] = tr16(vb + dn*128);
            b1[dn] = tr16(vb + dn*128 + 1024);
          }
          WAIT_LGKM0; SGB0;
          bf16x8 pa0 = __builtin_shufflevector(a00, a01, 0,1,2,3,4,5,6,7);
          bf16x8 pa1 = __builtin_shufflevector(a10, a11, 0,1,2,3,4,5,6,7);
          __builtin_amdgcn_s_setprio(1);
          #pragma unroll
          for (int dn = 0; dn < 8; ++dn) {
            bf16x8 v8 = __builtin_shufflevector(b0[dn], b1[dn], 0,1,2,3,4,5,6,7);
            oacc[0][dn] = __builtin_amdgcn_mfma_f32_16x16x32_bf16(pa0, v8, oacc[0][dn], 0, 0, 0);
            oacc[1][dn] = __builtin_amdgcn_mfma_f32_16x16x32_bf16(pa1, v8, oacc[1][dn], 0, 0, 0);
          }
          __builtin_amdgcn_s_setprio(0);
        }
      }

      WAIT_VM0;
      __builtin_amdgcn_s_barrier();
      SGB0;
    }

    const size_t obase = ((size_t)(b*SS + q0w)) * DIM + h*HD;
    #pragma unroll
    for (int m = 0; m < 2; ++m) {
      #pragma unroll
      for (int r = 0; r < 4; ++r) {
        float inv = 1.0f / lrun[m][r];
        int srow = m*16 + l4*4 + r;
        #pragma unroll
        for (int dn = 0; dn < 8; ++dn)
          O[obase + (size_t)srow*DIM + dn*16 + l15] = f2bf(oacc[m][dn][r] * inv);
      }
    }
  }
}

extern "C" void kernel_launch(void* const* d_in, const int* in_sizes, int n_in,
                              void* d_out, int out_size, void* d_ws, size_t ws_size,
                              hipStream_t stream) {
  const float* x   = (const float*)d_in[0];
  const float* Wq  = (const float*)d_in[1];
  const float* Wkv = (const float*)d_in[2];
  const float* Wo  = (const float*)d_in[3];

  if (ws_size < (160ull << 20)) return;
  char* ws = (char*)d_ws;
  u16* xb   = (u16*)(ws);                  // 32 MB [4096][4096]
  u16* Wqb  = (u16*)(ws + (32ull  << 20)); // 32 MB [4096][4096]  \ fused W rows 0..6143
  u16* Wkvb = (u16*)(ws + (64ull  << 20)); // 16 MB [2048][4096]  /
  u16* Wob  = (u16*)(ws + (80ull  << 20)); // 32 MB [4096][4096]
  u16* QKVb = (u16*)(ws + (112ull << 20)); // 48 MB [4096][6144]
  u16* attnb = xb;                         // alias after projections

  // fp32 -> bf16, one launch (x | Wq | Wkv | Wo)
  f2b4_kernel<<<28672, 256, 0, stream>>>(x, Wq, Wkv, Wo, xb, Wqb, Wkvb, Wob);

  // fused QKV projection: [4096][6144] = xb @ [Wq;Wkv]^T ; QSCALE on Q cols only
  // grid 768 blocks (16 x 48), 2 blocks/CU resident
  gemm256<0><<<dim3(768), 256, 0, stream>>>(xb, Wqb, QKVb,
                                            MROWS, QKVP, DIM, 48, DIM, QSCALE, 1.0f);

  attn_kernel<<<dim3(8, NHEADS, BB), 256, 0, stream>>>(QKVb, attnb);

  // output projection (fp32 out), grid 512 blocks (16 x 32) = exactly 2/CU
  gemm256<1><<<dim3(512), 256, 0, stream>>>(attnb, Wob, d_out,
                                            MROWS, DIM, DIM, 32, 0, 1.0f, 1.0f);
}

// Round 13
// 534.939 us; speedup vs baseline: 1.2934x; 1.0130x over previous
//
#include <hip/hip_runtime.h>

typedef __bf16 bf16x8 __attribute__((ext_vector_type(8)));
typedef __bf16 bf16x4 __attribute__((ext_vector_type(4)));
typedef float f32x4 __attribute__((ext_vector_type(4)));
typedef unsigned short u16;
typedef unsigned short u16x8 __attribute__((ext_vector_type(8)));

#define DIM 4096
#define NHEADS 32
#define NKV 8
#define HD 128
#define BB 2
#define SS 2048
#define MROWS (BB*SS)        // 4096
#define QKVP 6144            // fused QKV row pitch (4096 Q | 1024 K | 1024 V)
#define QSCALE 0.08838834764831843f  // 1/sqrt(128)

#define WAIT_LGKM0 asm volatile("s_waitcnt lgkmcnt(0)" ::: "memory")
#define WAIT_VM0   asm volatile("s_waitcnt vmcnt(0)" ::: "memory")
#define WAIT_VM6   asm volatile("s_waitcnt vmcnt(6)" ::: "memory")
#define SGB0       __builtin_amdgcn_sched_barrier(0)

__device__ __forceinline__ u16 f2bf(float f) {
  unsigned int u = __float_as_uint(f);
  u += 0x7fffu + ((u >> 16) & 1u);   // round-to-nearest-even
  return (u16)(u >> 16);
}

__device__ __forceinline__ void gload16(const void* g, void* l) {
  __builtin_amdgcn_global_load_lds(
      (const __attribute__((address_space(1))) unsigned int*)g,
      (__attribute__((address_space(3))) unsigned int*)l, 16, 0, 0);
}

__device__ __forceinline__ bf16x4 tr16(const void* p) {
  bf16x4 d;
  asm volatile("ds_read_b64_tr_b16 %0, %1"
               : "=v"(d)
               : "v"((const __attribute__((address_space(3))) u16*)p)
               : "memory");
  return d;
}

template<int CTRL>
__device__ __forceinline__ float dpp_ror(float x) {
  return __int_as_float(__builtin_amdgcn_update_dpp(
      0, __float_as_int(x), CTRL, 0xF, 0xF, false));
}
__device__ __forceinline__ float red16_max(float v) {
  v = fmaxf(v, dpp_ror<0x121>(v));
  v = fmaxf(v, dpp_ror<0x122>(v));
  v = fmaxf(v, dpp_ror<0x124>(v));
  v = fmaxf(v, dpp_ror<0x128>(v));
  return v;
}
__device__ __forceinline__ float red16_sum(float v) {
  v += dpp_ror<0x121>(v);
  v += dpp_ror<0x122>(v);
  v += dpp_ror<0x124>(v);
  v += dpp_ror<0x128>(v);
  return v;
}

// ---------------- fp32 -> bf16 conversion, all 4 tensors in one launch ----------------
__global__ __launch_bounds__(256) void f2b4_kernel(
    const float* __restrict__ xa, const float* __restrict__ xb,
    const float* __restrict__ xc, const float* __restrict__ xd,
    u16* __restrict__ oa, u16* __restrict__ ob,
    u16* __restrict__ oc, u16* __restrict__ od) {
  int i = blockIdx.x * 256 + threadIdx.x;
  const float* in; u16* out; int k;
  if (i < 2097152)      { in = xa; out = oa; k = i; }
  else if (i < 4194304) { in = xb; out = ob; k = i - 2097152; }
  else if (i < 5242880) { in = xc; out = oc; k = i - 4194304; }
  else                  { in = xd; out = od; k = i - 5242880; }
  const float4* in4 = (const float4*)in;
  float4 a = in4[2*(size_t)k];
  float4 b = in4[2*(size_t)k + 1];
  u16x8 o;
  o[0]=f2bf(a.x); o[1]=f2bf(a.y); o[2]=f2bf(a.z); o[3]=f2bf(a.w);
  o[4]=f2bf(b.x); o[5]=f2bf(b.y); o[6]=f2bf(b.z); o[7]=f2bf(b.w);
  ((u16x8*)out)[k] = o;
}

// ---------------- 256x128 / BK=32 / 4-wave GEMM, C = A @ B^T ----------------
// R12 schedule (reg-dbuf + 3-ring counted vmcnt, 2 blocks/CU) + 2D XCD-
// locality mapping: XCD x owns column-stripe bx in [x*W, x*W+W), W=nbx/8
// (O-proj W=4 -> 4MB B per XCD = L2-resident; QKV W=6). Within stripe,
// bx-minor/by-major sweep: co-resident same-by blocks reuse A-panels in L2.
// Mechanism under test: all prior schedule variants plateau where L2-miss
// demand (~blocks x 3MB = 2.3GB) hits ~10 TB/s -> memory-system-bound, not
// schedule-bound. This mapping cuts per-XCD L2 inflow ~96MB -> ~36MB.
// LDS per buf: A 16KB @0, B 8KB @16384; ldsrow j (128B) holds tile rows
// {2j,2j+1}; stored 16B-chunk c = src chunk ^ (j&7) (rule 21).
template<int OUTF32>
__global__ __launch_bounds__(256, 2) void gemm256(
    const u16* __restrict__ A, const u16* __restrict__ Bm, void* __restrict__ C,
    int M, int N, int K, int nbx, int acut, float a0, float a1) {
  __shared__ char smem[73728];            // 3 bufs x 24576

  const int t = threadIdx.x;
  const int l = t & 63, w = t >> 6;
  const int l15 = l & 15, l4 = l >> 4;
  const int wm = w >> 1, wn = w & 1;      // 2 x 2 wave grid, wave-tile 128x64

  // 2D XCD-locality mapping (bijective: nwg = 8 * W * nby exactly)
  const int W = nbx >> 3;                 // column-stripe width per XCD
  const int q = blockIdx.x >> 3;
  const int bx = (blockIdx.x & 7) * W + q % W;
  const int by = q / W;
  const int row0 = by * 256, col0 = bx * 128;
  const float alpha = (col0 < acut) ? a0 : a1;

  f32x4 acc[8][4] = {};

  // ---- stage addressing: A = 1024 16B-units (thread t: q*256+t, q=0..3),
  // B = 512 units (q=0..1). unit u: ldsrow j=u>>3, stored chunk u&7 holds
  // source chunk cs=(u&7)^(j&7); tile row r=2j+(cs>>2), k-off kc=(cs&3)*8.
  const u16* pA0; const u16* pA1; const u16* pA2; const u16* pA3;
  const u16* pB0; const u16* pB1;
  {
    int u, j, cs, r, kc;
    u = t;          j = u >> 3; cs = (u & 7) ^ (j & 7); r = 2*j + (cs >> 2); kc = (cs & 3)*8;
    pA0 = A + (size_t)(row0 + r) * K + kc;
    u = t + 256;    j = u >> 3; cs = (u & 7) ^ (j & 7); r = 2*j + (cs >> 2); kc = (cs & 3)*8;
    pA1 = A + (size_t)(row0 + r) * K + kc;
    u = t + 512;    j = u >> 3; cs = (u & 7) ^ (j & 7); r = 2*j + (cs >> 2); kc = (cs & 3)*8;
    pA2 = A + (size_t)(row0 + r) * K + kc;
    u = t + 768;    j = u >> 3; cs = (u & 7) ^ (j & 7); r = 2*j + (cs >> 2); kc = (cs & 3)*8;
    pA3 = A + (size_t)(row0 + r) * K + kc;
    u = t;          j = u >> 3; cs = (u & 7) ^ (j & 7); r = 2*j + (cs >> 2); kc = (cs & 3)*8;
    pB0 = Bm + (size_t)(col0 + r) * K + kc;
    u = t + 256;    j = u >> 3; cs = (u & 7) ^ (j & 7); r = 2*j + (cs >> 2); kc = (cs & 3)*8;
    pB1 = Bm + (size_t)(col0 + r) * K + kc;
  }

  auto stage = [&](int tile, int buf) {
    char* d = (char*)smem + buf * 24576 + w*1024;
    const int k0 = tile * 32;
    gload16(pA0 + k0, d);
    gload16(pA1 + k0, d + 4096);
    gload16(pA2 + k0, d + 8192);
    gload16(pA3 + k0, d + 12288);
    gload16(pB0 + k0, d + 16384);
    gload16(pB1 + k0, d + 20480);
  };

  // ---- fragment offsets (swizzle is mi/ni-invariant: step 1024 B) ----
  int offA0, offB0;
  {
    int r = wm*128 + l15, j = r >> 1;
    int c = ((r & 1)*4 + l4) ^ (j & 7);
    offA0 = j*128 + c*16;
    r = wn*64 + l15; j = r >> 1;
    c = ((r & 1)*4 + l4) ^ (j & 7);
    offB0 = 16384 + j*128 + c*16;
  }

  struct Frags { bf16x8 a0,a1,a2,a3,a4,a5,a6,a7,b0,b1,b2,b3; };
  Frags F0, F1;

  auto loadF = [&](Frags& F, int buf) {
    const char* Sb = (const char*)smem + buf * 24576;
    const char* Ab = Sb + offA0;
    const char* Bb = Sb + offB0;
    F.a0 = *(const bf16x8*)(Ab);
    F.a1 = *(const bf16x8*)(Ab + 1024);
    F.a2 = *(const bf16x8*)(Ab + 2048);
    F.a3 = *(const bf16x8*)(Ab + 3072);
    F.a4 = *(const bf16x8*)(Ab + 4096);
    F.a5 = *(const bf16x8*)(Ab + 5120);
    F.a6 = *(const bf16x8*)(Ab + 6144);
    F.a7 = *(const bf16x8*)(Ab + 7168);
    F.b0 = *(const bf16x8*)(Bb);
    F.b1 = *(const bf16x8*)(Bb + 1024);
    F.b2 = *(const bf16x8*)(Bb + 2048);
    F.b3 = *(const bf16x8*)(Bb + 3072);
  };

  auto mfmaC = [&](const Frags& F) {
    __builtin_amdgcn_s_setprio(1);
    acc[0][0] = __builtin_amdgcn_mfma_f32_16x16x32_bf16(F.a0, F.b0, acc[0][0], 0, 0, 0);
    acc[0][1] = __builtin_amdgcn_mfma_f32_16x16x32_bf16(F.a0, F.b1, acc[0][1], 0, 0, 0);
    acc[0][2] = __builtin_amdgcn_mfma_f32_16x16x32_bf16(F.a0, F.b2, acc[0][2], 0, 0, 0);
    acc[0][3] = __builtin_amdgcn_mfma_f32_16x16x32_bf16(F.a0, F.b3, acc[0][3], 0, 0, 0);
    acc[1][0] = __builtin_amdgcn_mfma_f32_16x16x32_bf16(F.a1, F.b0, acc[1][0], 0, 0, 0);
    acc[1][1] = __builtin_amdgcn_mfma_f32_16x16x32_bf16(F.a1, F.b1, acc[1][1], 0, 0, 0);
    acc[1][2] = __builtin_amdgcn_mfma_f32_16x16x32_bf16(F.a1, F.b2, acc[1][2], 0, 0, 0);
    acc[1][3] = __builtin_amdgcn_mfma_f32_16x16x32_bf16(F.a1, F.b3, acc[1][3], 0, 0, 0);
    acc[2][0] = __builtin_amdgcn_mfma_f32_16x16x32_bf16(F.a2, F.b0, acc[2][0], 0, 0, 0);
    acc[2][1] = __builtin_amdgcn_mfma_f32_16x16x32_bf16(F.a2, F.b1, acc[2][1], 0, 0, 0);
    acc[2][2] = __builtin_amdgcn_mfma_f32_16x16x32_bf16(F.a2, F.b2, acc[2][2], 0, 0, 0);
    acc[2][3] = __builtin_amdgcn_mfma_f32_16x16x32_bf16(F.a2, F.b3, acc[2][3], 0, 0, 0);
    acc[3][0] = __builtin_amdgcn_mfma_f32_16x16x32_bf16(F.a3, F.b0, acc[3][0], 0, 0, 0);
    acc[3][1] = __builtin_amdgcn_mfma_f32_16x16x32_bf16(F.a3, F.b1, acc[3][1], 0, 0, 0);
    acc[3][2] = __builtin_amdgcn_mfma_f32_16x16x32_bf16(F.a3, F.b2, acc[3][2], 0, 0, 0);
    acc[3][3] = __builtin_amdgcn_mfma_f32_16x16x32_bf16(F.a3, F.b3, acc[3][3], 0, 0, 0);
    acc[4][0] = __builtin_amdgcn_mfma_f32_16x16x32_bf16(F.a4, F.b0, acc[4][0], 0, 0, 0);
    acc[4][1] = __builtin_amdgcn_mfma_f32_16x16x32_bf16(F.a4, F.b1, acc[4][1], 0, 0, 0);
    acc[4][2] = __builtin_amdgcn_mfma_f32_16x16x32_bf16(F.a4, F.b2, acc[4][2], 0, 0, 0);
    acc[4][3] = __builtin_amdgcn_mfma_f32_16x16x32_bf16(F.a4, F.b3, acc[4][3], 0, 0, 0);
    acc[5][0] = __builtin_amdgcn_mfma_f32_16x16x32_bf16(F.a5, F.b0, acc[5][0], 0, 0, 0);
    acc[5][1] = __builtin_amdgcn_mfma_f32_16x16x32_bf16(F.a5, F.b1, acc[5][1], 0, 0, 0);
    acc[5][2] = __builtin_amdgcn_mfma_f32_16x16x32_bf16(F.a5, F.b2, acc[5][2], 0, 0, 0);
    acc[5][3] = __builtin_amdgcn_mfma_f32_16x16x32_bf16(F.a5, F.b3, acc[5][3], 0, 0, 0);
    acc[6][0] = __builtin_amdgcn_mfma_f32_16x16x32_bf16(F.a6, F.b0, acc[6][0], 0, 0, 0);
    acc[6][1] = __builtin_amdgcn_mfma_f32_16x16x32_bf16(F.a6, F.b1, acc[6][1], 0, 0, 0);
    acc[6][2] = __builtin_amdgcn_mfma_f32_16x16x32_bf16(F.a6, F.b2, acc[6][2], 0, 0, 0);
    acc[6][3] = __builtin_amdgcn_mfma_f32_16x16x32_bf16(F.a6, F.b3, acc[6][3], 0, 0, 0);
    acc[7][0] = __builtin_amdgcn_mfma_f32_16x16x32_bf16(F.a7, F.b0, acc[7][0], 0, 0, 0);
    acc[7][1] = __builtin_amdgcn_mfma_f32_16x16x32_bf16(F.a7, F.b1, acc[7][1], 0, 0, 0);
    acc[7][2] = __builtin_amdgcn_mfma_f32_16x16x32_bf16(F.a7, F.b2, acc[7][2], 0, 0, 0);
    acc[7][3] = __builtin_amdgcn_mfma_f32_16x16x32_bf16(F.a7, F.b3, acc[7][3], 0, 0, 0);
    __builtin_amdgcn_s_setprio(0);
  };

  const int nt = K >> 5;                  // K-tiles of 32 (even)

  // prologue: 3 tiles in flight; tiles 0,1 landed (VM6); regs for tile 0
  stage(0, 0); stage(1, 1); stage(2, 2);
  WAIT_VM6;
  __builtin_amdgcn_s_barrier();
  loadF(F0, 0);
  WAIT_LGKM0; SGB0;

  int b3 = 0;                             // buf of current tile ( = i%3 )
  for (int i = 0; i < nt; i += 2) {
    {
      if (i + 3 < nt) stage(i + 3, b3);   // (i+3)%3 == i%3: WAR-safe
      const int bn = (b3 == 2) ? 0 : b3 + 1;
      if (i + 1 < nt) loadF(F1, bn);      // stage(i+1) landed (invariant)
      SGB0;
      mfmaC(F0);
      WAIT_LGKM0; SGB0;
      if (i + 3 < nt) { WAIT_VM6; } else { WAIT_VM0; }  // stage(i+2) landed
      __builtin_amdgcn_s_barrier();
      b3 = bn;
    }
    if (i + 1 < nt) {
      if (i + 4 < nt) stage(i + 4, b3);
      const int bn = (b3 == 2) ? 0 : b3 + 1;
      if (i + 2 < nt) loadF(F0, bn);
      SGB0;
      mfmaC(F1);
      WAIT_LGKM0; SGB0;
      if (i + 4 < nt) { WAIT_VM6; } else { WAIT_VM0; }
      __builtin_amdgcn_s_barrier();
      b3 = bn;
    }
  }

  // epilogue: C/D layout col=lane&15, row=(lane>>4)*4+reg
  #pragma unroll
  for (int mi = 0; mi < 8; ++mi) {
    #pragma unroll
    for (int ni = 0; ni < 4; ++ni) {
      #pragma unroll
      for (int r = 0; r < 4; ++r) {
        size_t rr = (size_t)(row0 + wm*128 + mi*16 + l4*4 + r);
        size_t cc = (size_t)(col0 + wn*64 + ni*16 + l15);
        float v = acc[mi][ni][r] * alpha;
        if (OUTF32) ((float*)C)[rr*(size_t)N + cc] = v;
        else        ((u16*)C)[rr*(size_t)N + cc] = f2bf(v);
      }
    }
  }
}

// ---------------- causal GQA flash attention (QKVP pitch) ----------------
__global__ __launch_bounds__(256, 2) void attn_kernel(
    const u16* __restrict__ QKV,  // [4096][6144]: 0..4095 Q | 4096..5119 K | 5120..6143 V
    u16* __restrict__ O) {        // [4096][4096]
  __shared__ u16 Ks[2][64*128];
  __shared__ u16 Vs[2][64*128];
  __shared__ u16 Ps[4][1024];
  const int t = threadIdx.x;
  const int l = t & 63, w = t >> 6;
  const int l15 = l & 15, l4 = l >> 4;
  const int pair = blockIdx.x, h = blockIdx.y, b = blockIdx.z;
  const int hkv = h >> 2;
  const u16* Kg = QKV + (size_t)(b*SS) * QKVP + DIM + hkv*HD;
  const u16* Vg = Kg + NKV*HD;
  u16* Pw = &Ps[w][0];

  auto stage = [&](u16* Ksb, u16* Vsb, int kv0) {
    const u16* Kr = Kg + (size_t)kv0 * QKVP;
    const u16* Vr = Vg + (size_t)kv0 * QKVP;
    #pragma unroll
    for (int i = 0; i < 4; ++i) {
      int o = i*4096 + w*1024 + l*16;
      int row = o >> 8;
      int sc = l15 ^ (row & 7);
      gload16((const char*)(Kr + (size_t)row * QKVP) + sc*16,
              (char*)Ksb + i*4096 + w*1024);
    }
    #pragma unroll
    for (int i = 0; i < 4; ++i) {
      int cb = i*4 + w;
      int kv = cb*4 + ((l & 7) >> 1);
      int d0 = ((l >> 3) << 4) + (l & 1)*8;
      gload16((const char*)(Vr + (size_t)kv * QKVP + d0),
              (char*)Vsb + cb*1024);
    }
  };

  for (int half = 0; half < 2; ++half) {
    const int qb = half ? (15 - pair) : pair;
    const int q0 = qb * 128;
    const int q0w = q0 + w*32;

    const size_t qbase = ((size_t)(b*SS + q0w)) * QKVP + h*HD;
    bf16x8 qf[2][4];
    #pragma unroll
    for (int m = 0; m < 2; ++m)
      #pragma unroll
      for (int kd = 0; kd < 4; ++kd)
        qf[m][kd] = *(const bf16x8*)&QKV[qbase + (size_t)(m*16 + l15)*QKVP + kd*32 + l4*8];

    f32x4 oacc[2][8] = {};
    float mrun[2][4], lrun[2][4];
    #pragma unroll
    for (int m = 0; m < 2; ++m)
      #pragma unroll
      for (int r = 0; r < 4; ++r) { mrun[m][r] = -1e30f; lrun[m][r] = 0.f; }

    const int nst = 2*qb + 2;
    stage(Ks[0], Vs[0], 0);
    WAIT_VM0;
    __builtin_amdgcn_s_barrier();
    SGB0;

    for (int st = 0; st < nst; ++st) {
      const int kv0 = st * 64;
      u16* Ksb = Ks[st & 1];
      u16* Vsb = Vs[st & 1];
      if (st + 1 < nst) stage(Ks[(st+1) & 1], Vs[(st+1) & 1], kv0 + 64);

      if (kv0 <= q0w + 31) {
        f32x4 sacc[2][4] = {};
        __builtin_amdgcn_s_setprio(1);
        #pragma unroll
        for (int kd = 0; kd < 4; ++kd) {
          bf16x8 kf[4];
          #pragma unroll
          for (int n = 0; n < 4; ++n) {
            int row = n*16 + l15;
            int off = (row << 8) | (((kd*4 + l4) ^ (row & 7)) << 4);
            kf[n] = *(const bf16x8*)((const char*)Ksb + off);
          }
          #pragma unroll
          for (int m = 0; m < 2; ++m)
            #pragma unroll
            for (int n = 0; n < 4; ++n)
              sacc[m][n] = __builtin_amdgcn_mfma_f32_16x16x32_bf16(qf[m][kd], kf[n], sacc[m][n], 0, 0, 0);
        }
        __builtin_amdgcn_s_setprio(0);

        if (st >= 2*qb) {
          #pragma unroll
          for (int n = 0; n < 4; ++n) {
            int ki = kv0 + n*16 + l15;
            #pragma unroll
            for (int m = 0; m < 2; ++m)
              #pragma unroll
              for (int r = 0; r < 4; ++r) {
                int qi = q0w + m*16 + l4*4 + r;
                if (ki > qi) sacc[m][n][r] = -1e30f;
              }
          }
        }

        float pr[2][4][4];
        #pragma unroll
        for (int m = 0; m < 2; ++m) {
          #pragma unroll
          for (int r = 0; r < 4; ++r) {
            float s0 = sacc[m][0][r], s1 = sacc[m][1][r];
            float s2 = sacc[m][2][r], s3 = sacc[m][3][r];
            float vm = fmaxf(fmaxf(s0, s1), fmaxf(s2, s3));
            vm = red16_max(vm);
            float mo = mrun[m][r];
            float mnew = fmaxf(mo, vm);
            float al = __expf(mo - mnew);
            float p0 = __expf(s0 - mnew), p1 = __expf(s1 - mnew);
            float p2 = __expf(s2 - mnew), p3 = __expf(s3 - mnew);
            float rs = red16_sum((p0 + p1) + (p2 + p3));
            mrun[m][r] = mnew;
            lrun[m][r] = lrun[m][r]*al + rs;
            #pragma unroll
            for (int dn = 0; dn < 8; ++dn) oacc[m][dn][r] *= al;
            pr[m][r][0] = p0; pr[m][r][1] = p1; pr[m][r][2] = p2; pr[m][r][3] = p3;
          }
        }

        #pragma unroll
        for (int kvh = 0; kvh < 2; ++kvh) {
          #pragma unroll
          for (int m = 0; m < 2; ++m)
            #pragma unroll
            for (int nn = 0; nn < 2; ++nn) {
              int n = kvh*2 + nn;
              bf16x4 w4;
              w4[0] = (__bf16)pr[m][0][n]; w4[1] = (__bf16)pr[m][1][n];
              w4[2] = (__bf16)pr[m][2][n]; w4[3] = (__bf16)pr[m][3][n];
              *(bf16x4*)((char*)Pw + ((nn*4 + (l15 >> 2))*2 + m)*128
                                   + (l15 & 3)*32 + l4*8) = w4;
            }
          const char* pb = (const char*)Pw + l4*512 + l15*8;
          bf16x4 a00 = tr16(pb);
          bf16x4 a01 = tr16(pb + 256);
          bf16x4 a10 = tr16(pb + 128);
          bf16x4 a11 = tr16(pb + 384);
          const char* vb = (const char*)Vsb + l4*2048 + l15*8 + kvh*8192;
          bf16x4 b0[8], b1[8];
          #pragma unroll
          for (int dn = 0; dn < 8; ++dn) {
            b0[dn] = tr16(vb + dn*128);
            b1[dn] = tr16(vb + dn*128 + 1024);
          }
          WAIT_LGKM0; SGB0;
          bf16x8 pa0 = __builtin_shufflevector(a00, a01, 0,1,2,3,4,5,6,7);
          bf16x8 pa1 = __builtin_shufflevector(a10, a11, 0,1,2,3,4,5,6,7);
          __builtin_amdgcn_s_setprio(1);
          #pragma unroll
          for (int dn = 0; dn < 8; ++dn) {
            bf16x8 v8 = __builtin_shufflevector(b0[dn], b1[dn], 0,1,2,3,4,5,6,7);
            oacc[0][dn] = __builtin_amdgcn_mfma_f32_16x16x32_bf16(pa0, v8, oacc[0][dn], 0, 0, 0);
            oacc[1][dn] = __builtin_amdgcn_mfma_f32_16x16x32_bf16(pa1, v8, oacc[1][dn], 0, 0, 0);
          }
          __builtin_amdgcn_s_setprio(0);
        }
      }

      WAIT_VM0;
      __builtin_amdgcn_s_barrier();
      SGB0;
    }

    const size_t obase = ((size_t)(b*SS + q0w)) * DIM + h*HD;
    #pragma unroll
    for (int m = 0; m < 2; ++m) {
      #pragma unroll
      for (int r = 0; r < 4; ++r) {
        float inv = 1.0f / lrun[m][r];
        int srow = m*16 + l4*4 + r;
        #pragma unroll
        for (int dn = 0; dn < 8; ++dn)
          O[obase + (size_t)srow*DIM + dn*16 + l15] = f2bf(oacc[m][dn][r] * inv);
      }
    }
  }
}

extern "C" void kernel_launch(void* const* d_in, const int* in_sizes, int n_in,
                              void* d_out, int out_size, void* d_ws, size_t ws_size,
                              hipStream_t stream) {
  const float* x   = (const float*)d_in[0];
  const float* Wq  = (const float*)d_in[1];
  const float* Wkv = (const float*)d_in[2];
  const float* Wo  = (const float*)d_in[3];

  if (ws_size < (160ull << 20)) return;
  char* ws = (char*)d_ws;
  u16* xb   = (u16*)(ws);                  // 32 MB [4096][4096]
  u16* Wqb  = (u16*)(ws + (32ull  << 20)); // 32 MB [4096][4096]  \ fused W rows 0..6143
  u16* Wkvb = (u16*)(ws + (64ull  << 20)); // 16 MB [2048][4096]  /
  u16* Wob  = (u16*)(ws + (80ull  << 20)); // 32 MB [4096][4096]
  u16* QKVb = (u16*)(ws + (112ull << 20)); // 48 MB [4096][6144]
  u16* attnb = xb;                         // alias after projections

  // fp32 -> bf16, one launch (x | Wq | Wkv | Wo)
  f2b4_kernel<<<28672, 256, 0, stream>>>(x, Wq, Wkv, Wo, xb, Wqb, Wkvb, Wob);

  // fused QKV projection: [4096][6144] = xb @ [Wq;Wkv]^T ; QSCALE on Q cols only
  // grid 768 = 8 XCD x 6 bx x 16 by (2 blocks/CU resident)
  gemm256<0><<<dim3(768), 256, 0, stream>>>(xb, Wqb, QKVb,
                                            MROWS, QKVP, DIM, 48, DIM, QSCALE, 1.0f);

  attn_kernel<<<dim3(8, NHEADS, BB), 256, 0, stream>>>(QKVb, attnb);

  // output projection (fp32 out), grid 512 = 8 XCD x 4 bx x 16 by = 2/CU
  gemm256<1><<<dim3(512), 256, 0, stream>>>(attnb, Wob, d_out,
                                            MROWS, DIM, DIM, 32, 0, 1.0f, 1.0f);
}